// Round 1
// baseline (61.489 us; speedup 1.0000x reference)
//
#include <hip/hip_runtime.h>

#define NSAMP 256
#define PATCH 16
#define IMGD  224
#define MAXC  208   // IMG - PATCH
#define BATCH 128

// Kernel 1: compute coords, counting-sort per batch (x and y independently).
__global__ __launch_bounds__(256) void coord_sort_kernel(
        const float* __restrict__ mu,
        const float* __restrict__ beta,
        const float* __restrict__ noise,
        int* __restrict__ sx,
        int* __restrict__ sy) {
    const int b = blockIdx.x;
    const int s = threadIdx.x;

    __shared__ int histx[209], histy[209];
    __shared__ int prefx[209], prefy[209];
    if (s < 209) { histx[s] = 0; histy[s] = 0; }
    __syncthreads();

    const float mx = mu[b * 2 + 0], my = mu[b * 2 + 1];
    const float bx = beta[b * 2 + 0], by = beta[b * 2 + 1];
    const float nx = noise[(b * NSAMP + s) * 2 + 0];
    const float ny = noise[(b * NSAMP + s) * 2 + 1];

    // Match numpy exactly: separate mul and add (no FMA), round-half-even.
    float xf = __fadd_rn(__fmul_rn(bx, nx), mx);
    float yf = __fadd_rn(__fmul_rn(by, ny), my);
    xf = fminf(fmaxf(xf, 0.0f), 1.0f);
    yf = fminf(fmaxf(yf, 0.0f), 1.0f);
    xf = rintf(__fmul_rn(xf, (float)IMGD));   // v_rndne_f32: half-to-even
    yf = rintf(__fmul_rn(yf, (float)IMGD));
    const int xi = (int)fminf(fmaxf(xf, 0.0f), (float)MAXC);
    const int yi = (int)fminf(fmaxf(yf, 0.0f), (float)MAXC);

    atomicAdd(&histx[xi], 1);
    atomicAdd(&histy[yi], 1);
    __syncthreads();

    if (s == 0) {
        int ax = 0, ay = 0;
        for (int v = 0; v < 209; ++v) {
            prefx[v] = ax; ax += histx[v];
            prefy[v] = ay; ay += histy[v];
        }
    }
    __syncthreads();

    if (s < 209) {
        int st = prefx[s], cnt = histx[s];
        for (int k = 0; k < cnt; ++k) sx[b * NSAMP + st + k] = s;
        st = prefy[s]; cnt = histy[s];
        for (int k = 0; k < cnt; ++k) sy[b * NSAMP + st + k] = s;
    }
}

// Kernel 2: one block per (b, s, c); thread t=(i*16+j) copies one pixel.
// Output flat layout: ((b*NSAMP + s)*3 + c)*256 + i*16 + j.
__global__ __launch_bounds__(256) void gather_kernel(
        const float* __restrict__ image,
        const int* __restrict__ sx,
        const int* __restrict__ sy,
        float* __restrict__ out) {
    const int blk = blockIdx.x;        // (b*NSAMP + s)*3 + c
    const int c  = blk % 3;
    const int bs = blk / 3;            // b*NSAMP + s
    const int b  = bs / NSAMP;
    const int t  = threadIdx.x;
    const int i  = t >> 4;
    const int j  = t & 15;

    const int x = sx[bs];
    const int y = sy[bs];

    const float v = image[(((size_t)(b * 3 + c)) * IMGD + (x + i)) * IMGD + (y + j)];
    out[(size_t)blk * 256 + t] = v;
}

extern "C" void kernel_launch(void* const* d_in, const int* in_sizes, int n_in,
                              void* d_out, int out_size, void* d_ws, size_t ws_size,
                              hipStream_t stream) {
    const float* image = (const float*)d_in[0];
    const float* mu    = (const float*)d_in[1];
    const float* beta  = (const float*)d_in[2];
    const float* noise = (const float*)d_in[3];
    float* out = (float*)d_out;

    int* sx = (int*)d_ws;                         // BATCH*NSAMP ints
    int* sy = sx + (size_t)BATCH * NSAMP;         // BATCH*NSAMP ints

    coord_sort_kernel<<<BATCH, 256, 0, stream>>>(mu, beta, noise, sx, sy);

    const int nblk = BATCH * NSAMP * 3;           // 98304
    gather_kernel<<<nblk, 256, 0, stream>>>(image, sx, sy, out);
}

// Round 2
// 46.637 us; speedup vs baseline: 1.3185x; 1.3185x over previous
//
#include <hip/hip_runtime.h>

#define NSAMP 256
#define PATCH 16
#define IMGD  224
#define MAXC  208   // IMG - PATCH
#define BATCH 128

// Kernel 1: compute coords, counting-sort per batch (x and y independently).
__global__ __launch_bounds__(256) void coord_sort_kernel(
        const float* __restrict__ mu,
        const float* __restrict__ beta,
        const float* __restrict__ noise,
        int* __restrict__ sx,
        int* __restrict__ sy) {
    const int b = blockIdx.x;
    const int s = threadIdx.x;

    __shared__ int histx[209], histy[209];
    __shared__ int prefx[209], prefy[209];
    if (s < 209) { histx[s] = 0; histy[s] = 0; }
    __syncthreads();

    const float mx = mu[b * 2 + 0], my = mu[b * 2 + 1];
    const float bx = beta[b * 2 + 0], by = beta[b * 2 + 1];
    const float nx = noise[(b * NSAMP + s) * 2 + 0];
    const float ny = noise[(b * NSAMP + s) * 2 + 1];

    // Match numpy exactly: separate mul and add (no FMA), round-half-even.
    float xf = __fadd_rn(__fmul_rn(bx, nx), mx);
    float yf = __fadd_rn(__fmul_rn(by, ny), my);
    xf = fminf(fmaxf(xf, 0.0f), 1.0f);
    yf = fminf(fmaxf(yf, 0.0f), 1.0f);
    xf = rintf(__fmul_rn(xf, (float)IMGD));   // v_rndne_f32: half-to-even
    yf = rintf(__fmul_rn(yf, (float)IMGD));
    const int xi = (int)fminf(fmaxf(xf, 0.0f), (float)MAXC);
    const int yi = (int)fminf(fmaxf(yf, 0.0f), (float)MAXC);

    atomicAdd(&histx[xi], 1);
    atomicAdd(&histy[yi], 1);
    __syncthreads();

    if (s == 0) {
        int ax = 0, ay = 0;
        for (int v = 0; v < 209; ++v) {
            prefx[v] = ax; ax += histx[v];
            prefy[v] = ay; ay += histy[v];
        }
    }
    __syncthreads();

    if (s < 209) {
        int st = prefx[s], cnt = histx[s];
        for (int k = 0; k < cnt; ++k) sx[b * NSAMP + st + k] = s;
        st = prefy[s]; cnt = histy[s];
        for (int k = 0; k < cnt; ++k) sy[b * NSAMP + st + k] = s;
    }
}

// Kernel 2: 64 threads per (b,s,c) patch-channel. Lane l: row i = l>>2,
// quad q = l&3 -> loads image[.., x+i, y+4q .. y+4q+3] (4 scalar dword
// loads, row base only 4B-aligned) and stores one aligned float4 to out.
// Output flat layout: ((b*NSAMP + s)*3 + c)*256 + i*16 + q*4.
__global__ __launch_bounds__(256) void gather_kernel(
        const float* __restrict__ image,
        const int* __restrict__ sx,
        const int* __restrict__ sy,
        float* __restrict__ out) {
    const int t  = threadIdx.x;
    const int px = blockIdx.x * 4 + (t >> 6);   // patch-channel index
    const int c  = px % 3;
    const int bs = px / 3;                       // b*NSAMP + s
    const int b  = bs / NSAMP;

    const int l = t & 63;
    const int i = l >> 2;
    const int q = l & 3;

    const int x = sx[bs];
    const int y = sy[bs];

    const float* row = image + (((size_t)(b * 3 + c)) * IMGD + (x + i)) * IMGD + y + q * 4;
    float4 v;
    v.x = row[0];
    v.y = row[1];
    v.z = row[2];
    v.w = row[3];

    float4* dst = (float4*)(out + (size_t)px * 256 + i * 16 + q * 4);
    *dst = v;
}

extern "C" void kernel_launch(void* const* d_in, const int* in_sizes, int n_in,
                              void* d_out, int out_size, void* d_ws, size_t ws_size,
                              hipStream_t stream) {
    const float* image = (const float*)d_in[0];
    const float* mu    = (const float*)d_in[1];
    const float* beta  = (const float*)d_in[2];
    const float* noise = (const float*)d_in[3];
    float* out = (float*)d_out;

    int* sx = (int*)d_ws;                         // BATCH*NSAMP ints
    int* sy = sx + (size_t)BATCH * NSAMP;         // BATCH*NSAMP ints

    coord_sort_kernel<<<BATCH, 256, 0, stream>>>(mu, beta, noise, sx, sy);

    const int nblk = BATCH * NSAMP * 3 / 4;       // 24576
    gather_kernel<<<nblk, 256, 0, stream>>>(image, sx, sy, out);
}

// Round 4
// 37.010 us; speedup vs baseline: 1.6614x; 1.2601x over previous
//
#include <hip/hip_runtime.h>

#define NSAMP 256
#define PATCH 16
#define IMGD  224
#define MAXC  208   // IMG - PATCH
#define BATCH 128

typedef float f32x4 __attribute__((ext_vector_type(4)));

// Kernel 1: compute coords, counting-sort per batch (x and y independently).
// Parallel Hillis-Steele scan replaces the serial 209-bin loop.
__global__ __launch_bounds__(256) void coord_sort_kernel(
        const float* __restrict__ mu,
        const float* __restrict__ beta,
        const float* __restrict__ noise,
        int* __restrict__ sx,
        int* __restrict__ sy) {
    const int b = blockIdx.x;
    const int s = threadIdx.x;

    __shared__ int hx[256], hy[256];
    hx[s] = 0; hy[s] = 0;
    __syncthreads();

    const float mx = mu[b * 2 + 0], my = mu[b * 2 + 1];
    const float bx = beta[b * 2 + 0], by = beta[b * 2 + 1];
    const float nx = noise[(b * NSAMP + s) * 2 + 0];
    const float ny = noise[(b * NSAMP + s) * 2 + 1];

    // Match numpy exactly: separate mul and add (no FMA), round-half-even.
    float xf = __fadd_rn(__fmul_rn(bx, nx), mx);
    float yf = __fadd_rn(__fmul_rn(by, ny), my);
    xf = fminf(fmaxf(xf, 0.0f), 1.0f);
    yf = fminf(fmaxf(yf, 0.0f), 1.0f);
    xf = rintf(__fmul_rn(xf, (float)IMGD));   // v_rndne_f32: half-to-even
    yf = rintf(__fmul_rn(yf, (float)IMGD));
    const int xi = (int)fminf(fmaxf(xf, 0.0f), (float)MAXC);
    const int yi = (int)fminf(fmaxf(yf, 0.0f), (float)MAXC);

    atomicAdd(&hx[xi], 1);
    atomicAdd(&hy[yi], 1);
    __syncthreads();

    const int cntx = hx[s], cnty = hy[s];   // save own bin counts

    // Inclusive Hillis-Steele scan over 256 bins (bins 209..255 are zero).
    #pragma unroll
    for (int off = 1; off < 256; off <<= 1) {
        const int ax = hx[s], ay = hy[s];
        const int bxv = (s >= off) ? hx[s - off] : 0;
        const int byv = (s >= off) ? hy[s - off] : 0;
        __syncthreads();
        hx[s] = ax + bxv;
        hy[s] = ay + byv;
        __syncthreads();
    }

    // Exclusive prefix = inclusive - own count.
    if (s < 209) {
        int st = hx[s] - cntx;
        for (int k = 0; k < cntx; ++k) sx[b * NSAMP + st + k] = s;
        st = hy[s] - cnty;
        for (int k = 0; k < cnty; ++k) sy[b * NSAMP + st + k] = s;
    }
}

// Kernel 2: each wave handles 4 patch-channels (px). Lane l: row i = l>>2,
// quad q = l&3. Batch all index+pixel loads (16 outstanding dword loads),
// then 4 nontemporal float4 stores (4 KB/wave).
// Output flat layout: px*256 + i*16 + q*4, px = (b*NSAMP+s)*3 + c.
__global__ __launch_bounds__(256) void gather_kernel(
        const float* __restrict__ image,
        const int* __restrict__ sx,
        const int* __restrict__ sy,
        float* __restrict__ out) {
    const int t = threadIdx.x;
    const int g = t >> 6;                    // wave id within block
    const int l = t & 63;
    const int i = l >> 2;
    const int q = l & 3;
    const int px0 = blockIdx.x * 16 + g;     // wave's first px, stride 4

    f32x4 v[4];
    #pragma unroll
    for (int j = 0; j < 4; ++j) {
        const int px = px0 + j * 4;
        const int c  = px % 3;
        const int bs = px / 3;               // b*NSAMP + s
        const int b  = bs >> 8;
        const int x  = sx[bs];
        const int y  = sy[bs];
        const float* row = image + (((size_t)(b * 3 + c)) * IMGD + (x + i)) * IMGD + y + q * 4;
        v[j].x = row[0];
        v[j].y = row[1];
        v[j].z = row[2];
        v[j].w = row[3];
    }
    #pragma unroll
    for (int j = 0; j < 4; ++j) {
        const int px = px0 + j * 4;
        f32x4* dst = (f32x4*)(out + (size_t)px * 256 + i * 16 + q * 4);
        __builtin_nontemporal_store(v[j], dst);
    }
}

extern "C" void kernel_launch(void* const* d_in, const int* in_sizes, int n_in,
                              void* d_out, int out_size, void* d_ws, size_t ws_size,
                              hipStream_t stream) {
    const float* image = (const float*)d_in[0];
    const float* mu    = (const float*)d_in[1];
    const float* beta  = (const float*)d_in[2];
    const float* noise = (const float*)d_in[3];
    float* out = (float*)d_out;

    int* sx = (int*)d_ws;                         // BATCH*NSAMP ints
    int* sy = sx + (size_t)BATCH * NSAMP;         // BATCH*NSAMP ints

    coord_sort_kernel<<<BATCH, 256, 0, stream>>>(mu, beta, noise, sx, sy);

    const int nblk = BATCH * NSAMP * 3 / 16;      // 6144 blocks, 16 px each
    gather_kernel<<<nblk, 256, 0, stream>>>(image, sx, sy, out);
}

// Round 5
// 34.462 us; speedup vs baseline: 1.7842x; 1.0739x over previous
//
#include <hip/hip_runtime.h>

#define NSAMP 256
#define PATCH 16
#define IMGD  224
#define MAXC  208   // IMG - PATCH
#define BATCH 128

typedef float f32x4 __attribute__((ext_vector_type(4)));

// Kernel 1: compute coords, counting-sort per batch (x and y independently).
// Parallel Hillis-Steele scan replaces the serial 209-bin loop.
__global__ __launch_bounds__(256) void coord_sort_kernel(
        const float* __restrict__ mu,
        const float* __restrict__ beta,
        const float* __restrict__ noise,
        int* __restrict__ sx,
        int* __restrict__ sy) {
    const int b = blockIdx.x;
    const int s = threadIdx.x;

    __shared__ int hx[256], hy[256];
    hx[s] = 0; hy[s] = 0;
    __syncthreads();

    const float mx = mu[b * 2 + 0], my = mu[b * 2 + 1];
    const float bx = beta[b * 2 + 0], by = beta[b * 2 + 1];
    const float nx = noise[(b * NSAMP + s) * 2 + 0];
    const float ny = noise[(b * NSAMP + s) * 2 + 1];

    // Match numpy exactly: separate mul and add (no FMA), round-half-even.
    float xf = __fadd_rn(__fmul_rn(bx, nx), mx);
    float yf = __fadd_rn(__fmul_rn(by, ny), my);
    xf = fminf(fmaxf(xf, 0.0f), 1.0f);
    yf = fminf(fmaxf(yf, 0.0f), 1.0f);
    xf = rintf(__fmul_rn(xf, (float)IMGD));   // v_rndne_f32: half-to-even
    yf = rintf(__fmul_rn(yf, (float)IMGD));
    const int xi = (int)fminf(fmaxf(xf, 0.0f), (float)MAXC);
    const int yi = (int)fminf(fmaxf(yf, 0.0f), (float)MAXC);

    atomicAdd(&hx[xi], 1);
    atomicAdd(&hy[yi], 1);
    __syncthreads();

    const int cntx = hx[s], cnty = hy[s];   // save own bin counts

    // Inclusive Hillis-Steele scan over 256 bins (bins 209..255 are zero).
    #pragma unroll
    for (int off = 1; off < 256; off <<= 1) {
        const int ax = hx[s], ay = hy[s];
        const int bxv = (s >= off) ? hx[s - off] : 0;
        const int byv = (s >= off) ? hy[s - off] : 0;
        __syncthreads();
        hx[s] = ax + bxv;
        hy[s] = ay + byv;
        __syncthreads();
    }

    // Exclusive prefix = inclusive - own count.
    if (s < 209) {
        int st = hx[s] - cntx;
        for (int k = 0; k < cntx; ++k) sx[b * NSAMP + st + k] = s;
        st = hy[s] - cnty;
        for (int k = 0; k < cnty; ++k) sy[b * NSAMP + st + k] = s;
    }
}

// Kernel 2: each wave handles 8 patch-channels (px). Lane l: row i = l>>2,
// quad q = l&3. Batch all index+pixel loads (32 outstanding dword loads per
// thread), then 8 nontemporal float4 stores (8 KB/wave).
// Output flat layout: px*256 + i*16 + q*4, px = (b*NSAMP+s)*3 + c.
__global__ __launch_bounds__(256) void gather_kernel(
        const float* __restrict__ image,
        const int* __restrict__ sx,
        const int* __restrict__ sy,
        float* __restrict__ out) {
    const int t = threadIdx.x;
    const int g = t >> 6;                    // wave id within block
    const int l = t & 63;
    const int i = l >> 2;
    const int q = l & 3;
    const int px0 = blockIdx.x * 32 + g;     // wave's first px, stride 4

    const float* rows[8];
    #pragma unroll
    for (int j = 0; j < 8; ++j) {
        const int px = px0 + j * 4;
        const int c  = px % 3;
        const int bs = px / 3;               // b*NSAMP + s
        const int b  = bs >> 8;
        const int x  = sx[bs];
        const int y  = sy[bs];
        rows[j] = image + (((size_t)(b * 3 + c)) * IMGD + (x + i)) * IMGD + y + q * 4;
    }

    f32x4 v[8];
    #pragma unroll
    for (int j = 0; j < 8; ++j) {
        v[j].x = rows[j][0];
        v[j].y = rows[j][1];
        v[j].z = rows[j][2];
        v[j].w = rows[j][3];
    }

    #pragma unroll
    for (int j = 0; j < 8; ++j) {
        const int px = px0 + j * 4;
        f32x4* dst = (f32x4*)(out + (size_t)px * 256 + i * 16 + q * 4);
        __builtin_nontemporal_store(v[j], dst);
    }
}

extern "C" void kernel_launch(void* const* d_in, const int* in_sizes, int n_in,
                              void* d_out, int out_size, void* d_ws, size_t ws_size,
                              hipStream_t stream) {
    const float* image = (const float*)d_in[0];
    const float* mu    = (const float*)d_in[1];
    const float* beta  = (const float*)d_in[2];
    const float* noise = (const float*)d_in[3];
    float* out = (float*)d_out;

    int* sx = (int*)d_ws;                         // BATCH*NSAMP ints
    int* sy = sx + (size_t)BATCH * NSAMP;         // BATCH*NSAMP ints

    coord_sort_kernel<<<BATCH, 256, 0, stream>>>(mu, beta, noise, sx, sy);

    const int nblk = BATCH * NSAMP * 3 / 32;      // 3072 blocks, 32 px each
    gather_kernel<<<nblk, 256, 0, stream>>>(image, sx, sy, out);
}

// Round 6
// 29.900 us; speedup vs baseline: 2.0565x; 1.1526x over previous
//
#include <hip/hip_runtime.h>

#define NSAMP 256
#define PATCH 16
#define IMGD  224
#define MAXC  208   // IMG - PATCH
#define BATCH 128

typedef float f32x4 __attribute__((ext_vector_type(4)));

// Fully fused: each block handles 32 patch-channels (px), all within ONE
// batch (32 divides 768 = 3*NSAMP exactly). The block redundantly recomputes
// its batch's coordinate counting-sort in LDS (24 blocks/batch do identical
// deterministic work), then gathers. No workspace, no second launch.
//
// Phase 1 (sort): thread s computes coords of sample s; LDS histogram over
// 209 bins; 256-wide Hillis-Steele scan; emit sorted values into sxl/syl.
// Phase 2 (gather): wave g, lane l=(i,q): 8 px per wave, 32 outstanding
// dword loads, then 8 nontemporal float4 stores (8 KB/wave).
// Output flat layout: px*256 + i*16 + q*4, px = (b*NSAMP+s)*3 + c.
__global__ __launch_bounds__(256) void fused_sample_kernel(
        const float* __restrict__ image,
        const float* __restrict__ mu,
        const float* __restrict__ beta,
        const float* __restrict__ noise,
        float* __restrict__ out) {
    const int t   = threadIdx.x;
    const int px0 = blockIdx.x * 32;          // block's first px
    const int b   = px0 / (3 * NSAMP);        // the single batch this block touches

    __shared__ int hx[256], hy[256];
    __shared__ int sxl[256], syl[256];
    hx[t] = 0; hy[t] = 0;
    __syncthreads();

    // ---- Phase 1: coords + counting sort for batch b ----
    {
        const float mx = mu[b * 2 + 0], my = mu[b * 2 + 1];
        const float bx = beta[b * 2 + 0], by = beta[b * 2 + 1];
        const float nx = noise[(b * NSAMP + t) * 2 + 0];
        const float ny = noise[(b * NSAMP + t) * 2 + 1];

        // Match numpy exactly: separate mul/add (no FMA), round-half-even.
        float xf = __fadd_rn(__fmul_rn(bx, nx), mx);
        float yf = __fadd_rn(__fmul_rn(by, ny), my);
        xf = fminf(fmaxf(xf, 0.0f), 1.0f);
        yf = fminf(fmaxf(yf, 0.0f), 1.0f);
        xf = rintf(__fmul_rn(xf, (float)IMGD));   // v_rndne_f32: half-to-even
        yf = rintf(__fmul_rn(yf, (float)IMGD));
        const int xi = (int)fminf(fmaxf(xf, 0.0f), (float)MAXC);
        const int yi = (int)fminf(fmaxf(yf, 0.0f), (float)MAXC);

        atomicAdd(&hx[xi], 1);
        atomicAdd(&hy[yi], 1);
    }
    __syncthreads();

    const int cntx = hx[t], cnty = hy[t];   // own bin counts

    // Inclusive Hillis-Steele scan over 256 bins (bins 209..255 are zero).
    #pragma unroll
    for (int off = 1; off < 256; off <<= 1) {
        const int ax = hx[t], ay = hy[t];
        const int bxv = (t >= off) ? hx[t - off] : 0;
        const int byv = (t >= off) ? hy[t - off] : 0;
        __syncthreads();
        hx[t] = ax + bxv;
        hy[t] = ay + byv;
        __syncthreads();
    }

    if (t < 209) {
        int st = hx[t] - cntx;
        for (int k = 0; k < cntx; ++k) sxl[st + k] = t;
        st = hy[t] - cnty;
        for (int k = 0; k < cnty; ++k) syl[st + k] = t;
    }
    __syncthreads();

    // ---- Phase 2: gather 32 px (8 per wave) ----
    const int g = t >> 6;                    // wave id within block
    const int l = t & 63;
    const int i = l >> 2;
    const int q = l & 3;
    const int pxw = px0 + g;                 // wave's first px, stride 4

    const float* rows[8];
    #pragma unroll
    for (int j = 0; j < 8; ++j) {
        const int px = pxw + j * 4;
        const int c  = px % 3;
        const int bs = px / 3;               // b*NSAMP + s
        const int s  = bs & (NSAMP - 1);
        const int x  = sxl[s];
        const int y  = syl[s];
        rows[j] = image + (((size_t)(b * 3 + c)) * IMGD + (x + i)) * IMGD + y + q * 4;
    }

    f32x4 v[8];
    #pragma unroll
    for (int j = 0; j < 8; ++j) {
        v[j].x = rows[j][0];
        v[j].y = rows[j][1];
        v[j].z = rows[j][2];
        v[j].w = rows[j][3];
    }

    #pragma unroll
    for (int j = 0; j < 8; ++j) {
        const int px = pxw + j * 4;
        f32x4* dst = (f32x4*)(out + (size_t)px * 256 + i * 16 + q * 4);
        __builtin_nontemporal_store(v[j], dst);
    }
}

extern "C" void kernel_launch(void* const* d_in, const int* in_sizes, int n_in,
                              void* d_out, int out_size, void* d_ws, size_t ws_size,
                              hipStream_t stream) {
    const float* image = (const float*)d_in[0];
    const float* mu    = (const float*)d_in[1];
    const float* beta  = (const float*)d_in[2];
    const float* noise = (const float*)d_in[3];
    float* out = (float*)d_out;

    const int nblk = BATCH * NSAMP * 3 / 32;      // 3072 blocks, 32 px each
    fused_sample_kernel<<<nblk, 256, 0, stream>>>(image, mu, beta, noise, out);
}

// Round 7
// 27.813 us; speedup vs baseline: 2.2108x; 1.0751x over previous
//
#include <hip/hip_runtime.h>

#define NSAMP 256
#define PATCH 16
#define IMGD  224
#define MAXC  208   // IMG - PATCH
#define BATCH 128

typedef float f32x4 __attribute__((ext_vector_type(4)));

// Fully fused: each block handles 64 patch-channels (px), all within ONE
// batch (64 divides 768 = 3*NSAMP exactly; 12 blocks/batch). The block
// redundantly recomputes its batch's coordinate counting-sort in LDS,
// then gathers. 16 px per wave -> 64 outstanding dword loads/thread,
// 16 KB nontemporal stores/wave.
// Output flat layout: px*256 + i*16 + q*4, px = (b*NSAMP+s)*3 + c.
__global__ __launch_bounds__(256) void fused_sample_kernel(
        const float* __restrict__ image,
        const float* __restrict__ mu,
        const float* __restrict__ beta,
        const float* __restrict__ noise,
        float* __restrict__ out) {
    const int t   = threadIdx.x;
    const int px0 = blockIdx.x * 64;          // block's first px
    const int b   = px0 / (3 * NSAMP);        // the single batch this block touches

    __shared__ int hx[256], hy[256];
    __shared__ int sxl[256], syl[256];
    hx[t] = 0; hy[t] = 0;
    __syncthreads();

    // ---- Phase 1: coords + counting sort for batch b ----
    {
        const float mx = mu[b * 2 + 0], my = mu[b * 2 + 1];
        const float bx = beta[b * 2 + 0], by = beta[b * 2 + 1];
        const float nx = noise[(b * NSAMP + t) * 2 + 0];
        const float ny = noise[(b * NSAMP + t) * 2 + 1];

        // Match numpy exactly: separate mul/add (no FMA), round-half-even.
        float xf = __fadd_rn(__fmul_rn(bx, nx), mx);
        float yf = __fadd_rn(__fmul_rn(by, ny), my);
        xf = fminf(fmaxf(xf, 0.0f), 1.0f);
        yf = fminf(fmaxf(yf, 0.0f), 1.0f);
        xf = rintf(__fmul_rn(xf, (float)IMGD));   // v_rndne_f32: half-to-even
        yf = rintf(__fmul_rn(yf, (float)IMGD));
        const int xi = (int)fminf(fmaxf(xf, 0.0f), (float)MAXC);
        const int yi = (int)fminf(fmaxf(yf, 0.0f), (float)MAXC);

        atomicAdd(&hx[xi], 1);
        atomicAdd(&hy[yi], 1);
    }
    __syncthreads();

    const int cntx = hx[t], cnty = hy[t];   // own bin counts

    // Inclusive Hillis-Steele scan over 256 bins (bins 209..255 are zero).
    #pragma unroll
    for (int off = 1; off < 256; off <<= 1) {
        const int ax = hx[t], ay = hy[t];
        const int bxv = (t >= off) ? hx[t - off] : 0;
        const int byv = (t >= off) ? hy[t - off] : 0;
        __syncthreads();
        hx[t] = ax + bxv;
        hy[t] = ay + byv;
        __syncthreads();
    }

    if (t < 209) {
        int st = hx[t] - cntx;
        for (int k = 0; k < cntx; ++k) sxl[st + k] = t;
        st = hy[t] - cnty;
        for (int k = 0; k < cnty; ++k) syl[st + k] = t;
    }
    __syncthreads();

    // ---- Phase 2: gather 64 px (16 per wave) ----
    const int g = t >> 6;                    // wave id within block
    const int l = t & 63;
    const int i = l >> 2;
    const int q = l & 3;
    const int pxw = px0 + g;                 // wave's first px, stride 4

    const float* rows[16];
    #pragma unroll
    for (int j = 0; j < 16; ++j) {
        const int px = pxw + j * 4;
        const int c  = px % 3;
        const int bs = px / 3;               // b*NSAMP + s
        const int s  = bs & (NSAMP - 1);
        const int x  = sxl[s];
        const int y  = syl[s];
        rows[j] = image + (((size_t)(b * 3 + c)) * IMGD + (x + i)) * IMGD + y + q * 4;
    }

    f32x4 v[16];
    #pragma unroll
    for (int j = 0; j < 16; ++j) {
        v[j].x = rows[j][0];
        v[j].y = rows[j][1];
        v[j].z = rows[j][2];
        v[j].w = rows[j][3];
    }

    #pragma unroll
    for (int j = 0; j < 16; ++j) {
        const int px = pxw + j * 4;
        f32x4* dst = (f32x4*)(out + (size_t)px * 256 + i * 16 + q * 4);
        __builtin_nontemporal_store(v[j], dst);
    }
}

extern "C" void kernel_launch(void* const* d_in, const int* in_sizes, int n_in,
                              void* d_out, int out_size, void* d_ws, size_t ws_size,
                              hipStream_t stream) {
    const float* image = (const float*)d_in[0];
    const float* mu    = (const float*)d_in[1];
    const float* beta  = (const float*)d_in[2];
    const float* noise = (const float*)d_in[3];
    float* out = (float*)d_out;

    const int nblk = BATCH * NSAMP * 3 / 64;      // 1536 blocks, 64 px each
    fused_sample_kernel<<<nblk, 256, 0, stream>>>(image, mu, beta, noise, out);
}

// Round 8
// 27.630 us; speedup vs baseline: 2.2254x; 1.0066x over previous
//
#include <hip/hip_runtime.h>

#define NSAMP 256
#define PATCH 16
#define IMGD  224
#define MAXC  208   // IMG - PATCH
#define BATCH 128

typedef float f32x4 __attribute__((ext_vector_type(4)));

// Fully fused: each block handles 64 patch-channels (px), all within ONE
// batch (64 divides 768 = 3*NSAMP exactly; 12 blocks/batch). The block
// redundantly recomputes its batch's coordinate counting-sort in LDS,
// then gathers. Scan is wave-level shfl (no barriers) + 1-barrier combine.
// 16 px per wave -> 64 outstanding dword loads/thread, 16 KB NT stores/wave.
// Output flat layout: px*256 + i*16 + q*4, px = (b*NSAMP+s)*3 + c.
__global__ __launch_bounds__(256) void fused_sample_kernel(
        const float* __restrict__ image,
        const float* __restrict__ mu,
        const float* __restrict__ beta,
        const float* __restrict__ noise,
        float* __restrict__ out) {
    const int t   = threadIdx.x;
    const int px0 = blockIdx.x * 64;          // block's first px
    const int b   = px0 / (3 * NSAMP);        // the single batch this block touches

    __shared__ int hx[256], hy[256];
    __shared__ int sxl[256], syl[256];
    __shared__ int wsx[4], wsy[4];
    hx[t] = 0; hy[t] = 0;
    __syncthreads();

    // ---- Phase 1: coords + histogram for batch b ----
    {
        const float mx = mu[b * 2 + 0], my = mu[b * 2 + 1];
        const float bx = beta[b * 2 + 0], by = beta[b * 2 + 1];
        const float nx = noise[(b * NSAMP + t) * 2 + 0];
        const float ny = noise[(b * NSAMP + t) * 2 + 1];

        // Match numpy exactly: separate mul/add (no FMA), round-half-even.
        float xf = __fadd_rn(__fmul_rn(bx, nx), mx);
        float yf = __fadd_rn(__fmul_rn(by, ny), my);
        xf = fminf(fmaxf(xf, 0.0f), 1.0f);
        yf = fminf(fmaxf(yf, 0.0f), 1.0f);
        xf = rintf(__fmul_rn(xf, (float)IMGD));   // v_rndne_f32: half-to-even
        yf = rintf(__fmul_rn(yf, (float)IMGD));
        const int xi = (int)fminf(fmaxf(xf, 0.0f), (float)MAXC);
        const int yi = (int)fminf(fmaxf(yf, 0.0f), (float)MAXC);

        atomicAdd(&hx[xi], 1);
        atomicAdd(&hy[yi], 1);
    }
    __syncthreads();

    const int cntx = hx[t], cnty = hy[t];    // own bin counts
    const int w    = t >> 6;                 // wave id
    const int lane = t & 63;

    // Wave-level inclusive scan (no barriers).
    int vx = cntx, vy = cnty;
    #pragma unroll
    for (int d = 1; d < 64; d <<= 1) {
        const int ux = __shfl_up(vx, d);
        const int uy = __shfl_up(vy, d);
        if (lane >= d) { vx += ux; vy += uy; }
    }
    if (lane == 63) { wsx[w] = vx; wsy[w] = vy; }
    __syncthreads();

    // Add totals of preceding waves -> inclusive scan over all 256 bins.
    #pragma unroll
    for (int k = 0; k < 3; ++k) {
        if (w > k) { vx += wsx[k]; vy += wsy[k]; }
    }

    // Exclusive prefix = inclusive - own count; emit sorted values.
    if (t < 209) {
        int st = vx - cntx;
        for (int k = 0; k < cntx; ++k) sxl[st + k] = t;
        st = vy - cnty;
        for (int k = 0; k < cnty; ++k) syl[st + k] = t;
    }
    __syncthreads();

    // ---- Phase 2: gather 64 px (16 per wave) ----
    const int i = lane >> 2;
    const int q = lane & 3;
    const int pxw = px0 + w;                 // wave's first px, stride 4

    const float* rows[16];
    #pragma unroll
    for (int j = 0; j < 16; ++j) {
        const int px = pxw + j * 4;
        const int c  = px % 3;
        const int bs = px / 3;               // b*NSAMP + s
        const int s  = bs & (NSAMP - 1);
        const int x  = sxl[s];
        const int y  = syl[s];
        rows[j] = image + (((size_t)(b * 3 + c)) * IMGD + (x + i)) * IMGD + y + q * 4;
    }

    f32x4 v[16];
    #pragma unroll
    for (int j = 0; j < 16; ++j) {
        v[j].x = rows[j][0];
        v[j].y = rows[j][1];
        v[j].z = rows[j][2];
        v[j].w = rows[j][3];
    }

    #pragma unroll
    for (int j = 0; j < 16; ++j) {
        const int px = pxw + j * 4;
        f32x4* dst = (f32x4*)(out + (size_t)px * 256 + i * 16 + q * 4);
        __builtin_nontemporal_store(v[j], dst);
    }
}

extern "C" void kernel_launch(void* const* d_in, const int* in_sizes, int n_in,
                              void* d_out, int out_size, void* d_ws, size_t ws_size,
                              hipStream_t stream) {
    const float* image = (const float*)d_in[0];
    const float* mu    = (const float*)d_in[1];
    const float* beta  = (const float*)d_in[2];
    const float* noise = (const float*)d_in[3];
    float* out = (float*)d_out;

    const int nblk = BATCH * NSAMP * 3 / 64;      // 1536 blocks, 64 px each
    fused_sample_kernel<<<nblk, 256, 0, stream>>>(image, mu, beta, noise, out);
}